// Round 16
// baseline (367.003 us; speedup 1.0000x reference)
//
#include <hip/hip_runtime.h>
#include <hip/hip_bf16.h>

#define B_   8
#define KS_  64
#define L_   4096
#define D_   1024
#define H_   16
#define HD_  64
#define SCALE_ 0.125f

typedef __attribute__((ext_vector_type(8))) short short8;
typedef __attribute__((ext_vector_type(8))) unsigned short ushort8;
typedef __attribute__((ext_vector_type(4))) unsigned short ushort4v;
typedef __attribute__((ext_vector_type(4))) float f32x4;

__device__ __forceinline__ unsigned short f2b(float f) {
  union { float f; unsigned u; } v; v.f = f;
  unsigned r = v.u + 0x7fffu + ((v.u >> 16) & 1u);
  return (unsigned short)(r >> 16);
}

typedef const __attribute__((address_space(1))) void gas_void;
typedef __attribute__((address_space(3))) void las_void;
__device__ __forceinline__ void gl2lds16(const void* g, void* l) {
  __builtin_amdgcn_global_load_lds((gas_void*)g, (las_void*)l, 16, 0, 0);
}

__device__ __forceinline__ void bar() {           // raw barrier: no vmcnt drain
  asm volatile("" ::: "memory");
  __builtin_amdgcn_s_barrier();
  asm volatile("" ::: "memory");
}
__device__ __forceinline__ void vm4() {           // counted vmcnt (T4)
  asm volatile("s_waitcnt vmcnt(4)" ::: "memory");
}

// ---------------------------------------------------------------------------
// ALL input conversions in one launch (12800 blocks):
//  blocks [0,4608):      weights (4x1Mx f32) + query -> bf16 (1 unit/thread)
//  blocks [4608,12800):  K and V tensors (grid-stride, 1r/1w stream each)
// ---------------------------------------------------------------------------
__global__ __launch_bounds__(256) void cvt_all(const float* __restrict__ wq,
                                               const float* __restrict__ wk,
                                               const float* __restrict__ wv,
                                               const float* __restrict__ wo,
                                               const float* __restrict__ query,
                                               const float* __restrict__ key,
                                               const float* __restrict__ value,
                                               unsigned short* __restrict__ wout,
                                               unsigned short* __restrict__ qout,
                                               unsigned short* __restrict__ kb,
                                               unsigned short* __restrict__ vb) {
  if (blockIdx.x < 4608) {
    int i = blockIdx.x * 256 + threadIdx.x;      // 1,179,648 f32x4 units exactly
    const float* src;
    unsigned short* dst;
    int off;
    if (i < (4 << 18)) {
      int seg = i >> 18;
      off = (i & 0x3ffff) << 2;
      src = (seg == 0) ? wq : (seg == 1) ? wk : (seg == 2) ? wv : wo;
      dst = wout + ((size_t)seg << 20);
    } else {
      off = (i - (4 << 18)) << 2;
      src = query;
      dst = qout;
    }
    f32x4 v = *(const f32x4*)(src + off);
    ushort4v o;
#pragma unroll
    for (int j = 0; j < 4; ++j) o[j] = f2b(v[j]);
    *(ushort4v*)(dst + off) = o;
  } else {
    const int bid = blockIdx.x - 4608;           // 0..8191
    const int half = 4096;
    const bool isV = bid >= half;
    const float* src    = isV ? value : key;
    unsigned short* dst = isV ? vb : kb;
    const int b2 = isV ? bid - half : bid;
    const int stride = half * 256;
    for (int i = b2 * 256 + threadIdx.x; i < 4194304; i += stride) {
      const f32x4* p = (const f32x4*)(src + (size_t)i * 8);
      f32x4 a = __builtin_nontemporal_load(p);
      f32x4 b = __builtin_nontemporal_load(p + 1);
      ushort8 o;
#pragma unroll
      for (int j = 0; j < 4; ++j) { o[j] = f2b(a[j]); o[j + 4] = f2b(b[j]); }
      *(ushort8*)(dst + (size_t)i * 8) = o;
    }
  }
}

// ---------------------------------------------------------------------------
// gemm_all: K-proj + V-proj + Q-proj in ONE launch (1032 blocks x 512 thr).
//  blocks [0,512):     C_k = K_in @ Wk^T   (XCD-chunked swizzle)
//  blocks [512,1024):  C_v = V_in @ Wv^T
//  blocks [1024,1032): C_q = Q_in @ Wq^T   (M=512 -> 2 m-tiles x 4 n-tiles)
//  Body = round-15 proven 256x256 8-phase GEMM (T2 swizzle (row>>1)&3 both
//  sides, counted vmcnt(4), setprio, rotated conflict-free epilogue).
//  Merging removes 2 launch gaps + the K->V inter-kernel drain (CUs pick up
//  V tiles as soon as their K tile finishes).
//  NOTE: 512-thr block => 2 waves/SIMD => 256 regs/wave hard cap
//  (128 arch + 128 acc). Never attempt >1 block/CU at this tile size.
// ---------------------------------------------------------------------------
__global__ __launch_bounds__(512, 2) void gemm_all(
    const unsigned short* __restrict__ A_k, const unsigned short* __restrict__ A_v,
    const unsigned short* __restrict__ A_q,
    const unsigned short* __restrict__ W_k, const unsigned short* __restrict__ W_v,
    const unsigned short* __restrict__ W_q,
    unsigned short* __restrict__ C_k, unsigned short* __restrict__ C_v,
    unsigned short* __restrict__ C_q) {
  __shared__ __align__(16) char smem[131072];
  const int tid = threadIdx.x, lane = tid & 63, w = tid >> 6;
  const int g = lane >> 4, c15 = lane & 15;
  const int wm = w >> 2, wn = w & 3;

  const unsigned short *Ap, *Wp;
  unsigned short* Cp;
  long m0;
  int  n0;
  if (blockIdx.x < 1024) {
    const bool isV = blockIdx.x >= 512;
    const int  bb  = isV ? blockIdx.x - 512 : blockIdx.x;
    Ap = isV ? A_v : A_k;  Wp = isV ? W_v : W_k;  Cp = isV ? C_v : C_k;
    const int swz = (bb & 7) * 64 + (bb >> 3);
    m0 = (long)(swz >> 2) * 256;
    n0 = (swz & 3) * 256;
  } else {
    const int bb = blockIdx.x - 1024;            // 0..7
    Ap = A_q;  Wp = W_q;  Cp = C_q;
    m0 = (long)(bb >> 2) * 256;
    n0 = (bb & 3) * 256;
  }

  const int srow = w * 16 + (lane >> 2);
  const int cswz = (lane & 3) ^ ((lane >> 3) & 3);        // (srow>>1)&3
  const unsigned short* a_sr = Ap + (m0 + srow) * 1024 + cswz * 8;
  const unsigned short* b_sr = Wp + (long)(n0 + srow) * 1024 + cswz * 8;
  const int rswz = (g ^ ((c15 >> 1) & 3)) << 4;           // (row>>1)&3
  const int aoff = (wm * 128 + c15) * 64 + rswz;
  const int boff = 65536 + (wn * 64 + c15) * 64 + rswz;

  f32x4 acc[8][4] = {};
  short8 af[8], bf[2];

  auto STAGE_A = [&](int d, int kh, int tk) {
    char* dst = smem + d * 32768 + kh * 16384 + w * 1024;
    const unsigned short* src = a_sr + tk * 64 + kh * 32;
    gl2lds16(src,          dst);
    gl2lds16(src + 131072, dst + 8192);
  };
  auto STAGE_B = [&](int d, int kh, int tk) {
    char* dst = smem + 65536 + d * 32768 + kh * 16384 + w * 1024;
    const unsigned short* src = b_sr + tk * 64 + kh * 32;
    gl2lds16(src,          dst);
    gl2lds16(src + 131072, dst + 8192);
  };
  auto LDA = [&](int d, int ks) {
    const char* base = smem + d * 32768 + ks * 16384 + aoff;
#pragma unroll
    for (int m = 0; m < 8; ++m) af[m] = *(const short8*)(base + m * 1024);
  };
  auto LDB = [&](int d, int ks, int nh) {
    const char* base = smem + d * 32768 + ks * 16384 + boff + nh * 2048;
    bf[0] = *(const short8*)(base);
    bf[1] = *(const short8*)(base + 1024);
  };
  auto MM = [&](int nh) {
    __builtin_amdgcn_s_setprio(1);
#pragma unroll
    for (int n2 = 0; n2 < 2; ++n2)
#pragma unroll
      for (int m = 0; m < 8; ++m)
        acc[m][nh * 2 + n2] =
            __builtin_amdgcn_mfma_f32_16x16x32_bf16(af[m], bf[n2], acc[m][nh * 2 + n2], 0, 0, 0);
    __builtin_amdgcn_s_setprio(0);
  };

  STAGE_A(0, 0, 0); STAGE_B(0, 0, 0); STAGE_A(0, 1, 0); STAGE_B(0, 1, 0);
  vm4();
  bar();

#pragma unroll 1
  for (int tk = 0; tk < 16; tk += 2) {
    const bool more = (tk + 2 < 16);
    LDA(0, 0); LDB(0, 0, 0); STAGE_A(1, 0, tk + 1);          bar(); MM(0); bar();
    LDB(0, 0, 1);            STAGE_B(1, 0, tk + 1);  vm4();  bar(); MM(1); bar();
    LDA(0, 1); LDB(0, 1, 0); STAGE_A(1, 1, tk + 1);          bar(); MM(0); bar();
    LDB(0, 1, 1);            STAGE_B(1, 1, tk + 1);  vm4();  bar(); MM(1); bar();
    LDA(1, 0); LDB(1, 0, 0); if (more) STAGE_A(0, 0, tk + 2);        bar(); MM(0); bar();
    LDB(1, 0, 1);            if (more) STAGE_B(0, 0, tk + 2); vm4(); bar(); MM(1); bar();
    LDA(1, 1); LDB(1, 1, 0); if (more) STAGE_A(0, 1, tk + 2);        bar(); MM(0); bar();
    LDB(1, 1, 1);            if (more) STAGE_B(0, 1, tk + 2); vm4(); bar(); MM(1); bar();
  }

  unsigned short* cl = (unsigned short*)smem;
#pragma unroll
  for (int m = 0; m < 8; ++m)
#pragma unroll
    for (int n = 0; n < 4; ++n)
#pragma unroll
      for (int r = 0; r < 4; ++r)
        cl[(wm * 128 + m * 16 + g * 4 + r) * 256 + wn * 64 + n * 16 + c15] =
            f2b(acc[m][n][r]);
  __syncthreads();
  const int row = tid >> 1, half = tid & 1;
  unsigned short*       dst = Cp + (m0 + row) * 1024 + n0 + half * 128;
  const unsigned short* sl  = cl + row * 256 + half * 128;
#pragma unroll
  for (int i = 0; i < 16; ++i) {
    int c = (i + tid) & 15;     // rotated: pass lanes span all 8 bank-quads
    *(ushort8*)(dst + c * 8) = *(const ushort8*)(sl + c * 8);
  }
}

// ---------------------------------------------------------------------------
// 128x128 2-phase GEMM (proven) — O projection (bias + fp32 out)
// ---------------------------------------------------------------------------
__global__ __launch_bounds__(256) void gemm_o(const unsigned short* __restrict__ A,
                                              const unsigned short* __restrict__ W,
                                              float* __restrict__ Cf,
                                              const float* __restrict__ bias) {
  __shared__ __align__(16) char smem[34816];
  const int tid = threadIdx.x, lane = tid & 63, wv = tid >> 6;
  const int g = lane >> 4, c15 = lane & 15;
  const int wm = wv >> 1, wn = wv & 1;

  const int nwg = gridDim.x;
  const int swz = (blockIdx.x & 7) * (nwg >> 3) + (blockIdx.x >> 3);
  const long m0 = (long)(swz >> 3) * 128;
  const int  n0 = (swz & 7) * 128;

  const int srow = lane >> 2, scol = (lane & 3) * 8;
  const unsigned short* a_src = A + (m0 + srow) * 1024 + scol;
  const unsigned short* b_src = W + (long)(n0 + srow) * 1024 + scol;

  f32x4 acc[4][4] = {};

  auto stage = [&](int buf, int kt) {
    unsigned short* al = (unsigned short*)(smem + buf * 8192);
    unsigned short* bl = (unsigned short*)(smem + 16384 + buf * 8192);
#pragma unroll
    for (int q = 0; q < 2; ++q) {
      const int rbase = q * 64 + wv * 16;
      gl2lds16(a_src + (long)rbase * 1024 + kt * 32, al + rbase * 32);
      gl2lds16(b_src + (long)rbase * 1024 + kt * 32, bl + rbase * 32);
    }
  };

  stage(0, 0);
  __syncthreads();

  int cur = 0;
  for (int kt = 0; kt < 32; ++kt) {
    if (kt + 1 < 32) stage(cur ^ 1, kt + 1);
    const unsigned short* al = (const unsigned short*)(smem + cur * 8192);
    const unsigned short* bl = (const unsigned short*)(smem + 16384 + cur * 8192);
    short8 af[4];
#pragma unroll
    for (int m = 0; m < 4; ++m)
      af[m] = *(const short8*)&al[(wm * 64 + m * 16 + c15) * 32 + g * 8];
#pragma unroll
    for (int n = 0; n < 4; ++n) {
      short8 b8 = *(const short8*)&bl[(wn * 64 + n * 16 + c15) * 32 + g * 8];
#pragma unroll
      for (int m = 0; m < 4; ++m)
        acc[m][n] = __builtin_amdgcn_mfma_f32_16x16x32_bf16(af[m], b8, acc[m][n], 0, 0, 0);
    }
    __syncthreads();
    cur ^= 1;
  }

#pragma unroll
  for (int m = 0; m < 4; ++m)
#pragma unroll
    for (int n = 0; n < 4; ++n)
#pragma unroll
      for (int r = 0; r < 4; ++r) {
        long row = m0 + wm * 64 + m * 16 + g * 4 + r;
        int  col = n0 + wn * 64 + n * 16 + c15;
        Cf[row * 1024 + col] = acc[m][n][r] + bias[col];
      }
}

// ---------------------------------------------------------------------------
// Attention pass 1 (L-split x4): partial rowsums over 1024 keys per block.
// ---------------------------------------------------------------------------
__global__ __launch_bounds__(512) void attn_pass1(const unsigned short* __restrict__ q_b,
                                                  const unsigned short* __restrict__ k_b,
                                                  float* __restrict__ rs_part) {
  __shared__ unsigned short q_lds[64][72];
  __shared__ unsigned short k_lds[128][72];
  __shared__ float rs_lds[8][64];
  const int bh = blockIdx.x >> 2, ch = blockIdx.x & 3;
  const int b = bh >> 4, h = bh & 15;
  const int tid = threadIdx.x;
  const int w = tid >> 6, lane = tid & 63;
  const int g = lane >> 4, c15 = lane & 15;

  {
    int slot = tid >> 3, cc = (tid & 7) * 8;
    *(ushort8*)&q_lds[slot][cc] =
        *(const ushort8*)(q_b + (long)(b * 64 + slot) * 1024 + h * 64 + cc);
  }

  float rs[4][4] = {};
  const long kbase = (long)b * L_ * D_ + h * 64;
  const int  sl = tid >> 2, sc = (tid & 3) * 16;

  for (int it = ch * 8; it < ch * 8 + 8; ++it) {
    const int l0 = it * 128;
    ushort8 k0 = *(const ushort8*)(k_b + kbase + (long)(l0 + sl) * 1024 + sc);
    ushort8 k1 = *(const ushort8*)(k_b + kbase + (long)(l0 + sl) * 1024 + sc + 8);
    __syncthreads();
    *(ushort8*)&k_lds[sl][sc]     = k0;
    *(ushort8*)&k_lds[sl][sc + 8] = k1;
    __syncthreads();

    f32x4 s[4] = {};
#pragma unroll
    for (int ks = 0; ks < 2; ++ks) {
      short8 bf = *(const short8*)&k_lds[w * 16 + c15][ks * 32 + g * 8];
#pragma unroll
      for (int m = 0; m < 4; ++m) {
        short8 af = *(const short8*)&q_lds[m * 16 + c15][ks * 32 + g * 8];
        s[m] = __builtin_amdgcn_mfma_f32_16x16x32_bf16(af, bf, s[m], 0, 0, 0);
      }
    }
    float mx = -1e30f;
#pragma unroll
    for (int m = 0; m < 4; ++m)
#pragma unroll
      for (int r = 0; r < 4; ++r) mx = fmaxf(mx, s[m][r]);
    mx = fmaxf(mx, __shfl_xor(mx, 16));
    mx = fmaxf(mx, __shfl_xor(mx, 32));
    float sum = 0.f, p[4][4];
#pragma unroll
    for (int m = 0; m < 4; ++m)
#pragma unroll
      for (int r = 0; r < 4; ++r) { p[m][r] = __expf((s[m][r] - mx) * SCALE_); sum += p[m][r]; }
    sum += __shfl_xor(sum, 16);
    sum += __shfl_xor(sum, 32);
    float rinv = 1.0f / sum;
#pragma unroll
    for (int m = 0; m < 4; ++m)
#pragma unroll
      for (int r = 0; r < 4; ++r) rs[m][r] += p[m][r] * rinv;
  }
#pragma unroll
  for (int m = 0; m < 4; ++m)
#pragma unroll
    for (int r = 0; r < 4; ++r) {
      float v = rs[m][r];
      v += __shfl_xor(v, 1); v += __shfl_xor(v, 2);
      v += __shfl_xor(v, 4); v += __shfl_xor(v, 8);
      if (c15 == 0) rs_lds[w][m * 16 + g * 4 + r] = v;
    }
  __syncthreads();
  if (tid < 64) {
    float t = 0.f;
#pragma unroll
    for (int w2 = 0; w2 < 8; ++w2) t += rs_lds[w2][tid];
    rs_part[(bh * 4 + ch) * 64 + tid] = t;
  }
}

// ---------------------------------------------------------------------------
// Attention pass 2 (L-split x4): recompute softmax, scale, write attn fp32
// (nontemporal), PV partial -> op_part fp32.
// ---------------------------------------------------------------------------
__global__ __launch_bounds__(512) void attn_pass2(const unsigned short* __restrict__ q_b,
                                                  const unsigned short* __restrict__ k_b,
                                                  const unsigned short* __restrict__ v_b,
                                                  const float* __restrict__ rs_part,
                                                  float* __restrict__ attn,
                                                  float* __restrict__ op_part) {
  __shared__ unsigned short q_lds[64][72];
  __shared__ unsigned short k_lds[128][72];
  __shared__ unsigned short vt_lds[64][136];
  __shared__ unsigned short pt_lds[64][136];
  const int bh = blockIdx.x >> 2, ch = blockIdx.x & 3;
  const int b = bh >> 4, h = bh & 15;
  const int tid = threadIdx.x;
  const int w = tid >> 6, lane = tid & 63;
  const int g = lane >> 4, c15 = lane & 15;

  {
    int slot = tid >> 3, cc = (tid & 7) * 8;
    *(ushort8*)&q_lds[slot][cc] =
        *(const ushort8*)(q_b + (long)(b * 64 + slot) * 1024 + h * 64 + cc);
  }

  float inv_r[4][4];
#pragma unroll
  for (int m = 0; m < 4; ++m)
#pragma unroll
    for (int r = 0; r < 4; ++r) {
      int slot = m * 16 + g * 4 + r;
      float s = 0.f;
#pragma unroll
      for (int c = 0; c < 4; ++c) s += rs_part[(bh * 4 + c) * 64 + slot];
      inv_r[m][r] = 1.0f / (s + 1e-8f);
    }

  f32x4 oacc[2] = {};
  const int m_pv = w >> 1, n_pv0 = (w & 1) * 2;
  float* attn_base = attn + (long)bh * KS_ * L_;
  const long base_bld = (long)b * L_ * D_ + h * 64;
  const int  sl = tid >> 2, sc = (tid & 3) * 16;

  for (int it = ch * 8; it < ch * 8 + 8; ++it) {
    const int l0 = it * 128;
    ushort8 k0 = *(const ushort8*)(k_b + base_bld + (long)(l0 + sl) * 1024 + sc);
    ushort8 k1 = *(const ushort8*)(k_b + base_bld + (long)(l0 + sl) * 1024 + sc + 8);
    ushort8 v0 = *(const ushort8*)(v_b + base_bld + (long)(l0 + sl) * 1024 + sc);
    ushort8 v1 = *(const ushort8*)(v_b + base_bld + (long)(l0 + sl) * 1024 + sc + 8);
    __syncthreads();
    *(ushort8*)&k_lds[sl][sc]     = k0;
    *(ushort8*)&k_lds[sl][sc + 8] = k1;
#pragma unroll
    for (int j = 0; j < 8; ++j) {
      vt_lds[sc + j][sl]     = v0[j];
      vt_lds[sc + 8 + j][sl] = v1[j];
    }
    __syncthreads();

    f32x4 s[4] = {};
#pragma unroll
    for (int ks = 0; ks < 2; ++ks) {
      short8 bf = *(const short8*)&k_lds[w * 16 + c15][ks * 32 + g * 8];
#pragma unroll
      for (int m = 0; m < 4; ++m) {
        short8 af = *(const short8*)&q_lds[m * 16 + c15][ks * 32 + g * 8];
        s[m] = __builtin_amdgcn_mfma_f32_16x16x32_bf16(af, bf, s[m], 0, 0, 0);
      }
    }
    float mx = -1e30f;
#pragma unroll
    for (int m = 0; m < 4; ++m)
#pragma unroll
      for (int r = 0; r < 4; ++r) mx = fmaxf(mx, s[m][r]);
    mx = fmaxf(mx, __shfl_xor(mx, 16));
    mx = fmaxf(mx, __shfl_xor(mx, 32));
    float sum = 0.f, p[4][4];
#pragma unroll
    for (int m = 0; m < 4; ++m)
#pragma unroll
      for (int r = 0; r < 4; ++r) { p[m][r] = __expf((s[m][r] - mx) * SCALE_); sum += p[m][r]; }
    sum += __shfl_xor(sum, 16);
    sum += __shfl_xor(sum, 32);
    float rinv = 1.0f / sum;

    const int lloc = w * 16 + c15;
#pragma unroll
    for (int m = 0; m < 4; ++m)
#pragma unroll
      for (int r = 0; r < 4; ++r) {
        float ps = p[m][r] * rinv * inv_r[m][r];
        __builtin_nontemporal_store(ps,
            &attn_base[(long)(m * 16 + g * 4 + r) * L_ + l0 + lloc]);
        pt_lds[m * 16 + g * 4 + r][lloc] = f2b(ps);
      }
    __syncthreads();

#pragma unroll
    for (int ks = 0; ks < 4; ++ks) {
      short8 pa = *(const short8*)&pt_lds[m_pv * 16 + c15][ks * 32 + g * 8];
#pragma unroll
      for (int n2 = 0; n2 < 2; ++n2) {
        short8 vb = *(const short8*)&vt_lds[(n_pv0 + n2) * 16 + c15][ks * 32 + g * 8];
        oacc[n2] = __builtin_amdgcn_mfma_f32_16x16x32_bf16(pa, vb, oacc[n2], 0, 0, 0);
      }
    }
  }

#pragma unroll
  for (int n2 = 0; n2 < 2; ++n2)
#pragma unroll
    for (int r = 0; r < 4; ++r) {
      int slot = m_pv * 16 + g * 4 + r;
      int c    = (n_pv0 + n2) * 16 + c15;
      op_part[((long)(bh * 4 + ch) * 64 + slot) * 64 + c] = oacc[n2][r];
    }
}

// ---------------------------------------------------------------------------
// Reduce PV chunk-partials -> oh bf16 [512][1024]
// ---------------------------------------------------------------------------
__global__ __launch_bounds__(256) void oh_red(const float* __restrict__ op_part,
                                              unsigned short* __restrict__ oh) {
  int i = blockIdx.x * 256 + threadIdx.x;
  int c = i & 63, slot = (i >> 6) & 63, bh = i >> 12;
  float s = 0.f;
#pragma unroll
  for (int ch = 0; ch < 4; ++ch)
    s += op_part[((long)(bh * 4 + ch) * 64 + slot) * 64 + c];
  int b = bh >> 4, h = bh & 15;
  oh[(long)(b * 64 + slot) * 1024 + h * 64 + c] = f2b(s);
}

// ---------------------------------------------------------------------------
extern "C" void kernel_launch(void* const* d_in, const int* in_sizes, int n_in,
                              void* d_out, int out_size, void* d_ws, size_t ws_size,
                              hipStream_t stream) {
  (void)in_sizes; (void)n_in; (void)out_size; (void)ws_size;
  const float* query = (const float*)d_in[0];
  const float* key   = (const float*)d_in[1];
  const float* value = (const float*)d_in[2];
  const float* Wq    = (const float*)d_in[3];
  const float* Wk    = (const float*)d_in[4];
  const float* Wv    = (const float*)d_in[5];
  const float* Wo    = (const float*)d_in[6];
  const float* bo    = (const float*)d_in[7];

  char* ws = (char*)d_ws;
  unsigned short* w_all   = (unsigned short*)ws;                        // 8 MB
  unsigned short* wq_b    = w_all;
  unsigned short* wk_b    = w_all + (1u << 20);
  unsigned short* wv_b    = w_all + (2u << 20);
  unsigned short* wo_b    = w_all + (3u << 20);
  unsigned short* qin_b   = (unsigned short*)(ws + ((size_t)8  << 20)); // 1 MB
  unsigned short* q_b     = (unsigned short*)(ws + ((size_t)9  << 20)); // 1 MB
  unsigned short* oh_b    = (unsigned short*)(ws + ((size_t)10 << 20)); // 1 MB
  float*          rs_part = (float*)         (ws + ((size_t)11 << 20)); // 128 KB
  float*          op_part = (float*)         (ws + ((size_t)12 << 20)); // 8 MB
  unsigned short* k_b     = (unsigned short*)(ws + ((size_t)20 << 20)); // 64 MB
  unsigned short* v_b     = (unsigned short*)(ws + ((size_t)84 << 20)); // 64 MB

  float* out  = (float*)d_out;
  float* attn = out + (size_t)B_ * KS_ * D_;

  // converted K/V inputs live in the not-yet-written attn output region
  unsigned short* kin_b = (unsigned short*)attn;
  unsigned short* vin_b = (unsigned short*)attn + ((size_t)32 << 20);

  cvt_all<<<12800, 256, 0, stream>>>(Wq, Wk, Wv, Wo, query, key, value,
                                     w_all, qin_b, kin_b, vin_b);

  gemm_all<<<1032, 512, 0, stream>>>(kin_b, vin_b, qin_b,
                                     wk_b, wv_b, wq_b,
                                     k_b, v_b, q_b);

  attn_pass1<<<512, 512, 0, stream>>>(q_b, k_b, rs_part);
  attn_pass2<<<512, 512, 0, stream>>>(q_b, k_b, v_b, rs_part, attn, op_part);
  oh_red<<<2048, 256, 0, stream>>>(op_part, oh_b);

  gemm_o<<<32, 256, 0, stream>>>(oh_b, wo_b, out, bo);
}

// Round 17
// 362.383 us; speedup vs baseline: 1.0127x; 1.0127x over previous
//
#include <hip/hip_runtime.h>
#include <hip/hip_bf16.h>

#define B_   8
#define KS_  64
#define L_   4096
#define D_   1024
#define H_   16
#define HD_  64
#define SCALE_ 0.125f

typedef __attribute__((ext_vector_type(8))) short short8;
typedef __attribute__((ext_vector_type(8))) unsigned short ushort8;
typedef __attribute__((ext_vector_type(4))) unsigned short ushort4v;
typedef __attribute__((ext_vector_type(4))) float f32x4;

__device__ __forceinline__ unsigned short f2b(float f) {
  union { float f; unsigned u; } v; v.f = f;
  unsigned r = v.u + 0x7fffu + ((v.u >> 16) & 1u);
  return (unsigned short)(r >> 16);
}

typedef const __attribute__((address_space(1))) void gas_void;
typedef __attribute__((address_space(3))) void las_void;
__device__ __forceinline__ void gl2lds16(const void* g, void* l) {
  __builtin_amdgcn_global_load_lds((gas_void*)g, (las_void*)l, 16, 0, 0);
}

__device__ __forceinline__ void bar() {           // raw barrier: no vmcnt drain
  asm volatile("" ::: "memory");
  __builtin_amdgcn_s_barrier();
  asm volatile("" ::: "memory");
}
__device__ __forceinline__ void vm4() {           // counted vmcnt (T4)
  asm volatile("s_waitcnt vmcnt(4)" ::: "memory");
}

// ---------------------------------------------------------------------------
// ALL input conversions in one launch (12800 blocks):
//  blocks [0,4608):      weights (4x1M f32) + query -> bf16 (1 unit/thread)
//  blocks [4608,12800):  K and V tensors (grid-stride, 1r/1w stream each)
// ---------------------------------------------------------------------------
__global__ __launch_bounds__(256) void cvt_all(const float* __restrict__ wq,
                                               const float* __restrict__ wk,
                                               const float* __restrict__ wv,
                                               const float* __restrict__ wo,
                                               const float* __restrict__ query,
                                               const float* __restrict__ key,
                                               const float* __restrict__ value,
                                               unsigned short* __restrict__ wout,
                                               unsigned short* __restrict__ qout,
                                               unsigned short* __restrict__ kb,
                                               unsigned short* __restrict__ vb) {
  if (blockIdx.x < 4608) {
    int i = blockIdx.x * 256 + threadIdx.x;      // 1,179,648 f32x4 units exactly
    const float* src;
    unsigned short* dst;
    int off;
    if (i < (4 << 18)) {
      int seg = i >> 18;
      off = (i & 0x3ffff) << 2;
      src = (seg == 0) ? wq : (seg == 1) ? wk : (seg == 2) ? wv : wo;
      dst = wout + ((size_t)seg << 20);
    } else {
      off = (i - (4 << 18)) << 2;
      src = query;
      dst = qout;
    }
    f32x4 v = *(const f32x4*)(src + off);
    ushort4v o;
#pragma unroll
    for (int j = 0; j < 4; ++j) o[j] = f2b(v[j]);
    *(ushort4v*)(dst + off) = o;
  } else {
    const int bid = blockIdx.x - 4608;           // 0..8191
    const int half = 4096;
    const bool isV = bid >= half;
    const float* src    = isV ? value : key;
    unsigned short* dst = isV ? vb : kb;
    const int b2 = isV ? bid - half : bid;
    const int stride = half * 256;
    for (int i = b2 * 256 + threadIdx.x; i < 4194304; i += stride) {
      const f32x4* p = (const f32x4*)(src + (size_t)i * 8);
      f32x4 a = __builtin_nontemporal_load(p);
      f32x4 b = __builtin_nontemporal_load(p + 1);
      ushort8 o;
#pragma unroll
      for (int j = 0; j < 4; ++j) { o[j] = f2b(a[j]); o[j + 4] = f2b(b[j]); }
      *(ushort8*)(dst + (size_t)i * 8) = o;
    }
  }
}

// ---------------------------------------------------------------------------
// 256x256 8-phase GEMM (T2+T3+T4+T5): C[M][1024] = A(bf16) @ W(bf16)^T
//  Corrected T2 swizzle chunk^=(row>>1)&3 + rotated conflict-free epilogue.
//  NOTE: 512-thr block => 2 waves/SIMD => 256 regs/wave hard cap
//  (128 arch + 128 acc). Never attempt >1 block/CU at this tile size.
// ---------------------------------------------------------------------------
__global__ __launch_bounds__(512, 2) void gemm256(const unsigned short* __restrict__ A,
                                                  const unsigned short* __restrict__ W,
                                                  unsigned short* __restrict__ C) {
  __shared__ __align__(16) char smem[131072];
  const int tid = threadIdx.x, lane = tid & 63, w = tid >> 6;
  const int g = lane >> 4, c15 = lane & 15;
  const int wm = w >> 2, wn = w & 3;

  const int swz = (blockIdx.x & 7) * 64 + (blockIdx.x >> 3);
  const long m0 = (long)(swz >> 2) * 256;
  const int  n0 = (swz & 3) * 256;

  const int srow = w * 16 + (lane >> 2);
  const int cswz = (lane & 3) ^ ((lane >> 3) & 3);        // (srow>>1)&3
  const unsigned short* a_sr = A + (m0 + srow) * 1024 + cswz * 8;
  const unsigned short* b_sr = W + (long)(n0 + srow) * 1024 + cswz * 8;
  const int rswz = (g ^ ((c15 >> 1) & 3)) << 4;           // (row>>1)&3
  const int aoff = (wm * 128 + c15) * 64 + rswz;
  const int boff = 65536 + (wn * 64 + c15) * 64 + rswz;

  f32x4 acc[8][4] = {};
  short8 af[8], bf[2];

  auto STAGE_A = [&](int d, int kh, int tk) {
    char* dst = smem + d * 32768 + kh * 16384 + w * 1024;
    const unsigned short* src = a_sr + tk * 64 + kh * 32;
    gl2lds16(src,          dst);
    gl2lds16(src + 131072, dst + 8192);
  };
  auto STAGE_B = [&](int d, int kh, int tk) {
    char* dst = smem + 65536 + d * 32768 + kh * 16384 + w * 1024;
    const unsigned short* src = b_sr + tk * 64 + kh * 32;
    gl2lds16(src,          dst);
    gl2lds16(src + 131072, dst + 8192);
  };
  auto LDA = [&](int d, int ks) {
    const char* base = smem + d * 32768 + ks * 16384 + aoff;
#pragma unroll
    for (int m = 0; m < 8; ++m) af[m] = *(const short8*)(base + m * 1024);
  };
  auto LDB = [&](int d, int ks, int nh) {
    const char* base = smem + d * 32768 + ks * 16384 + boff + nh * 2048;
    bf[0] = *(const short8*)(base);
    bf[1] = *(const short8*)(base + 1024);
  };
  auto MM = [&](int nh) {
    __builtin_amdgcn_s_setprio(1);
#pragma unroll
    for (int n2 = 0; n2 < 2; ++n2)
#pragma unroll
      for (int m = 0; m < 8; ++m)
        acc[m][nh * 2 + n2] =
            __builtin_amdgcn_mfma_f32_16x16x32_bf16(af[m], bf[n2], acc[m][nh * 2 + n2], 0, 0, 0);
    __builtin_amdgcn_s_setprio(0);
  };

  STAGE_A(0, 0, 0); STAGE_B(0, 0, 0); STAGE_A(0, 1, 0); STAGE_B(0, 1, 0);
  vm4();
  bar();

#pragma unroll 1
  for (int tk = 0; tk < 16; tk += 2) {
    const bool more = (tk + 2 < 16);
    LDA(0, 0); LDB(0, 0, 0); STAGE_A(1, 0, tk + 1);          bar(); MM(0); bar();
    LDB(0, 0, 1);            STAGE_B(1, 0, tk + 1);  vm4();  bar(); MM(1); bar();
    LDA(0, 1); LDB(0, 1, 0); STAGE_A(1, 1, tk + 1);          bar(); MM(0); bar();
    LDB(0, 1, 1);            STAGE_B(1, 1, tk + 1);  vm4();  bar(); MM(1); bar();
    LDA(1, 0); LDB(1, 0, 0); if (more) STAGE_A(0, 0, tk + 2);        bar(); MM(0); bar();
    LDB(1, 0, 1);            if (more) STAGE_B(0, 0, tk + 2); vm4(); bar(); MM(1); bar();
    LDA(1, 1); LDB(1, 1, 0); if (more) STAGE_A(0, 1, tk + 2);        bar(); MM(0); bar();
    LDB(1, 1, 1);            if (more) STAGE_B(0, 1, tk + 2); vm4(); bar(); MM(1); bar();
  }

  unsigned short* cl = (unsigned short*)smem;
#pragma unroll
  for (int m = 0; m < 8; ++m)
#pragma unroll
    for (int n = 0; n < 4; ++n)
#pragma unroll
      for (int r = 0; r < 4; ++r)
        cl[(wm * 128 + m * 16 + g * 4 + r) * 256 + wn * 64 + n * 16 + c15] =
            f2b(acc[m][n][r]);
  __syncthreads();
  const int row = tid >> 1, half = tid & 1;
  unsigned short*       dst = C + (m0 + row) * 1024 + n0 + half * 128;
  const unsigned short* sl  = cl + row * 256 + half * 128;
#pragma unroll
  for (int i = 0; i < 16; ++i) {
    int c = (i + tid) & 15;     // rotated: pass lanes span all 8 bank-quads
    *(ushort8*)(dst + c * 8) = *(const ushort8*)(sl + c * 8);
  }
}

// ---------------------------------------------------------------------------
// 128x128 2-phase GEMM (proven) for the small projections (M=512)
// ---------------------------------------------------------------------------
template <bool OUT_F32B>
__global__ __launch_bounds__(256) void gemm_bf16(const unsigned short* __restrict__ A,
                                                 const unsigned short* __restrict__ W,
                                                 void* __restrict__ Cp,
                                                 const float* __restrict__ bias) {
  __shared__ __align__(16) char smem[34816];
  const int tid = threadIdx.x, lane = tid & 63, wv = tid >> 6;
  const int g = lane >> 4, c15 = lane & 15;
  const int wm = wv >> 1, wn = wv & 1;

  const int nwg = gridDim.x;
  const int swz = (blockIdx.x & 7) * (nwg >> 3) + (blockIdx.x >> 3);
  const long m0 = (long)(swz >> 3) * 128;
  const int  n0 = (swz & 7) * 128;

  const int srow = lane >> 2, scol = (lane & 3) * 8;
  const unsigned short* a_src = A + (m0 + srow) * 1024 + scol;
  const unsigned short* b_src = W + (long)(n0 + srow) * 1024 + scol;

  f32x4 acc[4][4] = {};

  auto stage = [&](int buf, int kt) {
    unsigned short* al = (unsigned short*)(smem + buf * 8192);
    unsigned short* bl = (unsigned short*)(smem + 16384 + buf * 8192);
#pragma unroll
    for (int q = 0; q < 2; ++q) {
      const int rbase = q * 64 + wv * 16;
      gl2lds16(a_src + (long)rbase * 1024 + kt * 32, al + rbase * 32);
      gl2lds16(b_src + (long)rbase * 1024 + kt * 32, bl + rbase * 32);
    }
  };

  stage(0, 0);
  __syncthreads();

  int cur = 0;
  for (int kt = 0; kt < 32; ++kt) {
    if (kt + 1 < 32) stage(cur ^ 1, kt + 1);
    const unsigned short* al = (const unsigned short*)(smem + cur * 8192);
    const unsigned short* bl = (const unsigned short*)(smem + 16384 + cur * 8192);
    short8 af[4];
#pragma unroll
    for (int m = 0; m < 4; ++m)
      af[m] = *(const short8*)&al[(wm * 64 + m * 16 + c15) * 32 + g * 8];
#pragma unroll
    for (int n = 0; n < 4; ++n) {
      short8 b8 = *(const short8*)&bl[(wn * 64 + n * 16 + c15) * 32 + g * 8];
#pragma unroll
      for (int m = 0; m < 4; ++m)
        acc[m][n] = __builtin_amdgcn_mfma_f32_16x16x32_bf16(af[m], b8, acc[m][n], 0, 0, 0);
    }
    __syncthreads();
    cur ^= 1;
  }

  if constexpr (OUT_F32B) {
    float* Cf = (float*)Cp;
#pragma unroll
    for (int m = 0; m < 4; ++m)
#pragma unroll
      for (int n = 0; n < 4; ++n)
#pragma unroll
        for (int r = 0; r < 4; ++r) {
          long row = m0 + wm * 64 + m * 16 + g * 4 + r;
          int  col = n0 + wn * 64 + n * 16 + c15;
          Cf[row * 1024 + col] = acc[m][n][r] + bias[col];
        }
  } else {
    unsigned short* c_lds = (unsigned short*)smem;
#pragma unroll
    for (int m = 0; m < 4; ++m)
#pragma unroll
      for (int n = 0; n < 4; ++n)
#pragma unroll
        for (int r = 0; r < 4; ++r)
          c_lds[(wm * 64 + m * 16 + g * 4 + r) * 132 + wn * 64 + n * 16 + c15] =
              f2b(acc[m][n][r]);
    __syncthreads();
    unsigned short* Cb = (unsigned short*)Cp;
    const int row = tid >> 1, half = tid & 1;
    unsigned short*       dst = Cb + (m0 + row) * 1024 + n0 + half * 64;
    const unsigned short* sl  = &c_lds[row * 132 + half * 64];
#pragma unroll
    for (int i = 0; i < 8; ++i)
      *(ushort8*)(dst + i * 8) = *(const ushort8*)(sl + i * 8);
  }
}

// ---------------------------------------------------------------------------
// Attention pass 1 (L-split x8): partial rowsums over 512 keys per block.
// 1024 blocks -> more memory parallelism (was 4.3 TB/s at 512 blocks).
// ---------------------------------------------------------------------------
__global__ __launch_bounds__(512) void attn_pass1(const unsigned short* __restrict__ q_b,
                                                  const unsigned short* __restrict__ k_b,
                                                  float* __restrict__ rs_part) {
  __shared__ unsigned short q_lds[64][72];
  __shared__ unsigned short k_lds[128][72];
  __shared__ float rs_lds[8][64];
  const int bh = blockIdx.x >> 3, ch = blockIdx.x & 7;
  const int b = bh >> 4, h = bh & 15;
  const int tid = threadIdx.x;
  const int w = tid >> 6, lane = tid & 63;
  const int g = lane >> 4, c15 = lane & 15;

  {
    int slot = tid >> 3, cc = (tid & 7) * 8;
    *(ushort8*)&q_lds[slot][cc] =
        *(const ushort8*)(q_b + (long)(b * 64 + slot) * 1024 + h * 64 + cc);
  }

  float rs[4][4] = {};
  const long kbase = (long)b * L_ * D_ + h * 64;
  const int  sl = tid >> 2, sc = (tid & 3) * 16;

  for (int it = ch * 4; it < ch * 4 + 4; ++it) {
    const int l0 = it * 128;
    ushort8 k0 = *(const ushort8*)(k_b + kbase + (long)(l0 + sl) * 1024 + sc);
    ushort8 k1 = *(const ushort8*)(k_b + kbase + (long)(l0 + sl) * 1024 + sc + 8);
    __syncthreads();
    *(ushort8*)&k_lds[sl][sc]     = k0;
    *(ushort8*)&k_lds[sl][sc + 8] = k1;
    __syncthreads();

    f32x4 s[4] = {};
#pragma unroll
    for (int ks = 0; ks < 2; ++ks) {
      short8 bf = *(const short8*)&k_lds[w * 16 + c15][ks * 32 + g * 8];
#pragma unroll
      for (int m = 0; m < 4; ++m) {
        short8 af = *(const short8*)&q_lds[m * 16 + c15][ks * 32 + g * 8];
        s[m] = __builtin_amdgcn_mfma_f32_16x16x32_bf16(af, bf, s[m], 0, 0, 0);
      }
    }
    float mx = -1e30f;
#pragma unroll
    for (int m = 0; m < 4; ++m)
#pragma unroll
      for (int r = 0; r < 4; ++r) mx = fmaxf(mx, s[m][r]);
    mx = fmaxf(mx, __shfl_xor(mx, 16));
    mx = fmaxf(mx, __shfl_xor(mx, 32));
    float sum = 0.f, p[4][4];
#pragma unroll
    for (int m = 0; m < 4; ++m)
#pragma unroll
      for (int r = 0; r < 4; ++r) { p[m][r] = __expf((s[m][r] - mx) * SCALE_); sum += p[m][r]; }
    sum += __shfl_xor(sum, 16);
    sum += __shfl_xor(sum, 32);
    float rinv = 1.0f / sum;
#pragma unroll
    for (int m = 0; m < 4; ++m)
#pragma unroll
      for (int r = 0; r < 4; ++r) rs[m][r] += p[m][r] * rinv;
  }
#pragma unroll
  for (int m = 0; m < 4; ++m)
#pragma unroll
    for (int r = 0; r < 4; ++r) {
      float v = rs[m][r];
      v += __shfl_xor(v, 1); v += __shfl_xor(v, 2);
      v += __shfl_xor(v, 4); v += __shfl_xor(v, 8);
      if (c15 == 0) rs_lds[w][m * 16 + g * 4 + r] = v;
    }
  __syncthreads();
  if (tid < 64) {
    float t = 0.f;
#pragma unroll
    for (int w2 = 0; w2 < 8; ++w2) t += rs_lds[w2][tid];
    rs_part[(bh * 8 + ch) * 64 + tid] = t;
  }
}

// ---------------------------------------------------------------------------
// Attention pass 2 (L-split x4): recompute softmax, scale, write attn fp32
// (nontemporal), PV partial -> op_part fp32. Rowsum gathers 8 pass-1 chunks.
// ---------------------------------------------------------------------------
__global__ __launch_bounds__(512) void attn_pass2(const unsigned short* __restrict__ q_b,
                                                  const unsigned short* __restrict__ k_b,
                                                  const unsigned short* __restrict__ v_b,
                                                  const float* __restrict__ rs_part,
                                                  float* __restrict__ attn,
                                                  float* __restrict__ op_part) {
  __shared__ unsigned short q_lds[64][72];
  __shared__ unsigned short k_lds[128][72];
  __shared__ unsigned short vt_lds[64][136];
  __shared__ unsigned short pt_lds[64][136];
  const int bh = blockIdx.x >> 2, ch = blockIdx.x & 3;
  const int b = bh >> 4, h = bh & 15;
  const int tid = threadIdx.x;
  const int w = tid >> 6, lane = tid & 63;
  const int g = lane >> 4, c15 = lane & 15;

  {
    int slot = tid >> 3, cc = (tid & 7) * 8;
    *(ushort8*)&q_lds[slot][cc] =
        *(const ushort8*)(q_b + (long)(b * 64 + slot) * 1024 + h * 64 + cc);
  }

  float inv_r[4][4];
#pragma unroll
  for (int m = 0; m < 4; ++m)
#pragma unroll
    for (int r = 0; r < 4; ++r) {
      int slot = m * 16 + g * 4 + r;
      float s = 0.f;
#pragma unroll
      for (int c = 0; c < 8; ++c) s += rs_part[(bh * 8 + c) * 64 + slot];
      inv_r[m][r] = 1.0f / (s + 1e-8f);
    }

  f32x4 oacc[2] = {};
  const int m_pv = w >> 1, n_pv0 = (w & 1) * 2;
  float* attn_base = attn + (long)bh * KS_ * L_;
  const long base_bld = (long)b * L_ * D_ + h * 64;
  const int  sl = tid >> 2, sc = (tid & 3) * 16;

  for (int it = ch * 8; it < ch * 8 + 8; ++it) {
    const int l0 = it * 128;
    ushort8 k0 = *(const ushort8*)(k_b + base_bld + (long)(l0 + sl) * 1024 + sc);
    ushort8 k1 = *(const ushort8*)(k_b + base_bld + (long)(l0 + sl) * 1024 + sc + 8);
    ushort8 v0 = *(const ushort8*)(v_b + base_bld + (long)(l0 + sl) * 1024 + sc);
    ushort8 v1 = *(const ushort8*)(v_b + base_bld + (long)(l0 + sl) * 1024 + sc + 8);
    __syncthreads();
    *(ushort8*)&k_lds[sl][sc]     = k0;
    *(ushort8*)&k_lds[sl][sc + 8] = k1;
#pragma unroll
    for (int j = 0; j < 8; ++j) {
      vt_lds[sc + j][sl]     = v0[j];
      vt_lds[sc + 8 + j][sl] = v1[j];
    }
    __syncthreads();

    f32x4 s[4] = {};
#pragma unroll
    for (int ks = 0; ks < 2; ++ks) {
      short8 bf = *(const short8*)&k_lds[w * 16 + c15][ks * 32 + g * 8];
#pragma unroll
      for (int m = 0; m < 4; ++m) {
        short8 af = *(const short8*)&q_lds[m * 16 + c15][ks * 32 + g * 8];
        s[m] = __builtin_amdgcn_mfma_f32_16x16x32_bf16(af, bf, s[m], 0, 0, 0);
      }
    }
    float mx = -1e30f;
#pragma unroll
    for (int m = 0; m < 4; ++m)
#pragma unroll
      for (int r = 0; r < 4; ++r) mx = fmaxf(mx, s[m][r]);
    mx = fmaxf(mx, __shfl_xor(mx, 16));
    mx = fmaxf(mx, __shfl_xor(mx, 32));
    float sum = 0.f, p[4][4];
#pragma unroll
    for (int m = 0; m < 4; ++m)
#pragma unroll
      for (int r = 0; r < 4; ++r) { p[m][r] = __expf((s[m][r] - mx) * SCALE_); sum += p[m][r]; }
    sum += __shfl_xor(sum, 16);
    sum += __shfl_xor(sum, 32);
    float rinv = 1.0f / sum;

    const int lloc = w * 16 + c15;
#pragma unroll
    for (int m = 0; m < 4; ++m)
#pragma unroll
      for (int r = 0; r < 4; ++r) {
        float ps = p[m][r] * rinv * inv_r[m][r];
        __builtin_nontemporal_store(ps,
            &attn_base[(long)(m * 16 + g * 4 + r) * L_ + l0 + lloc]);
        pt_lds[m * 16 + g * 4 + r][lloc] = f2b(ps);
      }
    __syncthreads();

#pragma unroll
    for (int ks = 0; ks < 4; ++ks) {
      short8 pa = *(const short8*)&pt_lds[m_pv * 16 + c15][ks * 32 + g * 8];
#pragma unroll
      for (int n2 = 0; n2 < 2; ++n2) {
        short8 vb = *(const short8*)&vt_lds[(n_pv0 + n2) * 16 + c15][ks * 32 + g * 8];
        oacc[n2] = __builtin_amdgcn_mfma_f32_16x16x32_bf16(pa, vb, oacc[n2], 0, 0, 0);
      }
    }
  }

#pragma unroll
  for (int n2 = 0; n2 < 2; ++n2)
#pragma unroll
    for (int r = 0; r < 4; ++r) {
      int slot = m_pv * 16 + g * 4 + r;
      int c    = (n_pv0 + n2) * 16 + c15;
      op_part[((long)(bh * 4 + ch) * 64 + slot) * 64 + c] = oacc[n2][r];
    }
}

// ---------------------------------------------------------------------------
// Reduce PV chunk-partials -> oh bf16 [512][1024]
// ---------------------------------------------------------------------------
__global__ __launch_bounds__(256) void oh_red(const float* __restrict__ op_part,
                                              unsigned short* __restrict__ oh) {
  int i = blockIdx.x * 256 + threadIdx.x;
  int c = i & 63, slot = (i >> 6) & 63, bh = i >> 12;
  float s = 0.f;
#pragma unroll
  for (int ch = 0; ch < 4; ++ch)
    s += op_part[((long)(bh * 4 + ch) * 64 + slot) * 64 + c];
  int b = bh >> 4, h = bh & 15;
  oh[(long)(b * 64 + slot) * 1024 + h * 64 + c] = f2b(s);
}

// ---------------------------------------------------------------------------
extern "C" void kernel_launch(void* const* d_in, const int* in_sizes, int n_in,
                              void* d_out, int out_size, void* d_ws, size_t ws_size,
                              hipStream_t stream) {
  (void)in_sizes; (void)n_in; (void)out_size; (void)ws_size;
  const float* query = (const float*)d_in[0];
  const float* key   = (const float*)d_in[1];
  const float* value = (const float*)d_in[2];
  const float* Wq    = (const float*)d_in[3];
  const float* Wk    = (const float*)d_in[4];
  const float* Wv    = (const float*)d_in[5];
  const float* Wo    = (const float*)d_in[6];
  const float* bo    = (const float*)d_in[7];

  char* ws = (char*)d_ws;
  unsigned short* w_all   = (unsigned short*)ws;                        // 8 MB
  unsigned short* wq_b    = w_all;
  unsigned short* wk_b    = w_all + (1u << 20);
  unsigned short* wv_b    = w_all + (2u << 20);
  unsigned short* wo_b    = w_all + (3u << 20);
  unsigned short* qin_b   = (unsigned short*)(ws + ((size_t)8  << 20)); // 1 MB
  unsigned short* q_b     = (unsigned short*)(ws + ((size_t)9  << 20)); // 1 MB
  unsigned short* oh_b    = (unsigned short*)(ws + ((size_t)10 << 20)); // 1 MB
  float*          rs_part = (float*)         (ws + ((size_t)11 << 20)); // 256 KB
  float*          op_part = (float*)         (ws + ((size_t)12 << 20)); // 8 MB
  unsigned short* k_b     = (unsigned short*)(ws + ((size_t)20 << 20)); // 64 MB
  unsigned short* v_b     = (unsigned short*)(ws + ((size_t)84 << 20)); // 64 MB

  float* out  = (float*)d_out;
  float* attn = out + (size_t)B_ * KS_ * D_;

  // converted K/V inputs live in the not-yet-written attn output region
  unsigned short* kin_b = (unsigned short*)attn;
  unsigned short* vin_b = (unsigned short*)attn + ((size_t)32 << 20);

  cvt_all<<<12800, 256, 0, stream>>>(Wq, Wk, Wv, Wo, query, key, value,
                                     w_all, qin_b, kin_b, vin_b);

  gemm_bf16<false><<<32, 256, 0, stream>>>(qin_b, wq_b, q_b, nullptr);
  gemm256<<<512, 512, 0, stream>>>(kin_b, wk_b, k_b);
  gemm256<<<512, 512, 0, stream>>>(vin_b, wv_b, v_b);

  attn_pass1<<<1024, 512, 0, stream>>>(q_b, k_b, rs_part);
  attn_pass2<<<512, 512, 0, stream>>>(q_b, k_b, v_b, rs_part, attn, op_part);
  oh_red<<<2048, 256, 0, stream>>>(op_part, oh_b);

  gemm_bf16<true><<<32, 256, 0, stream>>>(oh_b, wo_b, out, bo);
}